// Round 5
// baseline (918.423 us; speedup 1.0000x reference)
//
#include <hip/hip_runtime.h>
#include <hip/hip_bf16.h>
#include <cstddef>

#define BB 8
#define CC 512
#define NN 4096
#define CQ 64
#define MQ 64   // Q-rows per attn block (i-tile)
#define NJ 64   // j-tile

typedef short bf16x8 __attribute__((ext_vector_type(8)));
typedef float f32x4  __attribute__((ext_vector_type(4)));

// fp32 -> bf16 bits, round-to-nearest-even
static __device__ __forceinline__ unsigned bf16_bits(float f){
  unsigned u = __float_as_uint(f);
  u += 0x7fffu + ((u >> 16) & 1u);
  return u >> 16;
}
static __device__ __forceinline__ unsigned pack2bf(float lo, float hi){
  return bf16_bits(lo) | (bf16_bits(hi) << 16);
}

// ---- weights fp32 -> bf16 (Wqk packed: rows 0..63 = Wq, 64..127 = Wk) ----
__global__ __launch_bounds__(256) void cvt_w_kernel(
    const float* __restrict__ Wq, const float* __restrict__ Wk,
    const float* __restrict__ Wv,
    short* __restrict__ Wqkbf, short* __restrict__ Wvbf){
  const int i = blockIdx.x*256 + threadIdx.x;
  if (i < CQ*CC){
    Wqkbf[i]         = (short)bf16_bits(Wq[i]);
    Wqkbf[CQ*CC + i] = (short)bf16_bits(Wk[i]);
  }
  Wvbf[i] = (short)bf16_bits(Wv[i]);
}

// ---- x fp32 [b][c][n] -> xT bf16 [b][n][c] via LDS 64x64 tile ----
__global__ __launch_bounds__(256) void cvt_x_kernel(
    const float* __restrict__ x, short* __restrict__ xT){
  __shared__ float lds[64*67];
  const int tid = threadIdx.x;
  const int n0 = blockIdx.x*64, c0 = blockIdx.y*64, b = blockIdx.z;
  const int nl = tid & 63, cw = tid >> 6;
  const float* xp = x + ((size_t)b*CC + c0)*NN + n0;
#pragma unroll
  for (int i=0;i<16;++i){
    const int cl = cw*16 + i;
    lds[nl*67 + cl] = xp[(size_t)cl*NN + nl];
  }
  __syncthreads();
  short* xTp = xT + ((size_t)b*NN + n0)*CC + c0;
#pragma unroll
  for (int p=0;p<2;++p){
    const int nl2 = (tid>>3) + p*32;
    const int c8 = (tid&7)*8;
    const float* r = &lds[nl2*67 + c8];
    uint4 v;
    v.x = pack2bf(r[0], r[1]);
    v.y = pack2bf(r[2], r[3]);
    v.z = pack2bf(r[4], r[5]);
    v.w = pack2bf(r[6], r[7]);
    *(uint4*)&xTp[(size_t)nl2*CC + c8] = v;
  }
}

// ---- Q,K projection via MFMA: D[n][o] = xT . Wqk^T;  Qbf/Kbf layout [b][n][64] ----
// Q is pre-scaled by log2(e) so attn can use raw v_exp_f32 (2^x).
__global__ __launch_bounds__(256) void proj_qk_mfma(
    const short* __restrict__ xT, const short* __restrict__ Wqkbf,
    const float* __restrict__ bq, const float* __restrict__ bk,
    short* __restrict__ Qbf, short* __restrict__ Kbf){
  const int tid  = threadIdx.x;
  const int lane = tid & 63;
  const int w    = tid >> 6;
  const int iq   = lane & 15;
  const int q    = lane >> 4;
  const int b    = blockIdx.z;
  const int n0w  = blockIdx.x*128 + w*32;

  f32x4 acc[2][8];
#pragma unroll
  for (int ns=0;ns<2;++ns)
#pragma unroll
    for (int os=0;os<8;++os) acc[ns][os] = (f32x4){0.f,0.f,0.f,0.f};

  const short* Abase = xT + ((size_t)b*NN + n0w + iq)*CC + q*8;
  const short* Bbase = Wqkbf + (size_t)iq*CC + q*8;

  for (int ks=0; ks<16; ++ks){
    const int k = ks*32;
    bf16x8 af[2], bf[8];
#pragma unroll
    for (int ns=0;ns<2;++ns) af[ns] = *(const bf16x8*)(Abase + (size_t)ns*16*CC + k);
#pragma unroll
    for (int os=0;os<8;++os) bf[os] = *(const bf16x8*)(Bbase + (size_t)os*16*CC + k);
#pragma unroll
    for (int ns=0;ns<2;++ns)
#pragma unroll
      for (int os=0;os<8;++os)
        acc[ns][os] = __builtin_amdgcn_mfma_f32_16x16x32_bf16(af[ns], bf[os], acc[ns][os], 0,0,0);
  }
#pragma unroll
  for (int ns=0;ns<2;++ns){
#pragma unroll
    for (int os=0;os<8;++os){
      const int o = (os&4) ? ((os-4)*16 + iq) : (os*16 + iq);
      const float bias = (os<4) ? bq[o] : bk[o];
      short* dst = (os<4) ? Qbf : Kbf;
#pragma unroll
      for (int r=0;r<4;++r){
        const int n = n0w + ns*16 + q*4 + r;
        float v = acc[ns][os][r] + bias;
        if (os < 4) v *= 1.44269504088896f;  // fold log2(e) into Q
        dst[((size_t)b*NN + n)*CQ + o] = (short)bf16_bits(v);
      }
    }
  }
}

// ---- V projection via MFMA: D[c][n] = Wv . x;  Vbf layout [b][c][n] ----
__global__ __launch_bounds__(256) void proj_v_mfma(
    const short* __restrict__ xT, const short* __restrict__ Wvbf,
    const float* __restrict__ bv, short* __restrict__ Vbf){
  const int tid  = threadIdx.x;
  const int lane = tid & 63;
  const int w    = tid >> 6;
  const int iq   = lane & 15;
  const int q    = lane >> 4;
  const int b    = blockIdx.z;
  const int c0w  = blockIdx.y*128 + (w&1)*64;
  const int n0w  = blockIdx.x*64 + (w>>1)*32;

  f32x4 acc[4][2];
#pragma unroll
  for (int cs=0;cs<4;++cs)
#pragma unroll
    for (int ns=0;ns<2;++ns) acc[cs][ns] = (f32x4){0.f,0.f,0.f,0.f};

  const short* Abase = Wvbf + (size_t)(c0w + iq)*CC + q*8;
  const short* Bbase = xT + ((size_t)b*NN + n0w + iq)*CC + q*8;

  for (int ks=0; ks<16; ++ks){
    const int k = ks*32;
    bf16x8 af[4], bf[2];
#pragma unroll
    for (int cs=0;cs<4;++cs) af[cs] = *(const bf16x8*)(Abase + (size_t)cs*16*CC + k);
#pragma unroll
    for (int ns=0;ns<2;++ns) bf[ns] = *(const bf16x8*)(Bbase + (size_t)ns*16*CC + k);
#pragma unroll
    for (int cs=0;cs<4;++cs)
#pragma unroll
      for (int ns=0;ns<2;++ns)
        acc[cs][ns] = __builtin_amdgcn_mfma_f32_16x16x32_bf16(af[cs], bf[ns], acc[cs][ns], 0,0,0);
  }
#pragma unroll
  for (int cs=0;cs<4;++cs){
#pragma unroll
    for (int r=0;r<4;++r){
      const int c = c0w + cs*16 + q*4 + r;
      const float bias = bv[c];
#pragma unroll
      for (int ns=0;ns<2;++ns){
        const int n = n0w + ns*16 + iq;
        Vbf[((size_t)b*CC + c)*NN + n] = (short)bf16_bits(acc[cs][ns][r] + bias);
      }
    }
  }
}

// ---- MFMA flash attention, BARRIER-FREE (wave-independent tiles) ----
// Grid 1024: bid&7 = batch (XCD swizzle), (bid>>3)&1 = c-half (256 ch), bid>>4 = i-tile (64).
// Wave w = (ih = w>>1, cq = w&1): owns i in [i0+ih*32, +32), c in [ch+cq*128, +128).
// Each wave computes its own QK^T (P duplicated x2 across cq waves, +20% MFMA total),
// exps in-register, and fixes the P fragment layout (j: lane-q groups -> registers)
// through a WAVE-PRIVATE LDS scratch: write -> lgkmcnt(0) -> read. Same wave, so
// NO s_barrier anywhere; waves free-run and their MFMA/VALU/L2 phases overlap.
// LDS scratch per wave: 32 j-pairs x 32 i, dword stride 36 (bank-pad: <=2-way).
__global__ __launch_bounds__(256, 2) void attn_mfma_kernel(
    const short* __restrict__ Qbf, const short* __restrict__ Kbf,
    const short* __restrict__ Vbf, const float* __restrict__ x,
    const float* __restrict__ gamma, float* __restrict__ out){
  __shared__ unsigned pscr[4*32*36];   // 18.4 KB, wave-private quarters

  const int tid  = threadIdx.x;
  const int lane = tid & 63;
  const int w    = tid >> 6;
  const int iq   = lane & 15;
  const int q    = lane >> 4;
  const int bid  = blockIdx.x;
  const int b    = bid & 7;
  const int ch   = ((bid >> 3) & 1) * 256;
  const int i0   = (bid >> 4) * MQ;
  const int i0w  = i0 + (w >> 1) * 32;     // this wave's 32 i-rows
  const int c0w  = ch + (w & 1) * 128;     // this wave's 128 channels

  // Q B-frags for the wave's two i-groups (persistent; pre-scaled by log2e)
  bf16x8 qb[2][2];
#pragma unroll
  for (int s=0;s<2;++s){
    const short* qp = Qbf + ((size_t)b*NN + i0w + s*16 + iq)*CQ + q*8;
    qb[s][0] = *(const bf16x8*)qp;
    qb[s][1] = *(const bf16x8*)(qp + 32);
  }

  f32x4 acc[8][2];   // [cs=c/16][s=i-group]
#pragma unroll
  for (int cs=0;cs<8;++cs)
#pragma unroll
    for (int s=0;s<2;++s) acc[cs][s] = (f32x4){0.f,0.f,0.f,0.f};
  float lpart[2] = {0.f,0.f};

  const short* Kb = Kbf + ((size_t)b*NN + iq)*CQ + q*8;          // + (j0+jm*16)*CQ + oh*32
  const short* Vb = Vbf + ((size_t)b*CC + c0w + iq)*NN + q*8;    // + cs*16*NN + j0 + kh*32

  // LDS dword offsets (wave-private base w*1152):
  //  write (jm,s):  wa + jm*288 + s*16   (dword pair at +0 / +36)
  //  read (kh,s,d): ra + kh*576 + s*16 + d*36
  const int wa = w*1152 + q*72  + iq;
  const int ra = w*1152 + q*144 + iq;

  // K A-frags for jt=0 (reloaded each jt after QK consumes them)
  bf16x8 ka[4][2];
#pragma unroll
  for (int jm=0;jm<4;++jm)
#pragma unroll
    for (int oh=0;oh<2;++oh)
      ka[jm][oh] = *(const bf16x8*)(Kb + (size_t)(jm*16)*CQ + oh*32);

#pragma unroll 1
  for (int jt=0; jt<NN/NJ; ++jt){
    const int j0 = jt*NJ;

    // ---- V loads, first half (cs 0..3) ----
    bf16x8 va[8][2];
#pragma unroll
    for (int cs=0;cs<4;++cs)
#pragma unroll
      for (int kh=0;kh<2;++kh)
        va[cs][kh] = *(const bf16x8*)(Vb + (size_t)cs*16*NN + j0 + kh*32);

    // ---- S^T = K . Q^T : 16 MFMA (4 j-groups x 2 i-groups, K=64) ----
    f32x4 sf[4][2];
#pragma unroll
    for (int jm=0;jm<4;++jm)
#pragma unroll
      for (int s=0;s<2;++s){
        sf[jm][s] = __builtin_amdgcn_mfma_f32_16x16x32_bf16(ka[jm][0], qb[s][0], (f32x4){0.f,0.f,0.f,0.f}, 0,0,0);
        sf[jm][s] = __builtin_amdgcn_mfma_f32_16x16x32_bf16(ka[jm][1], qb[s][1], sf[jm][s], 0,0,0);
      }

    // ---- reload K for jt+1 (slack: exp+LDS+PV; overread past Kbf stays in workspace) ----
#pragma unroll
    for (int jm=0;jm<4;++jm)
#pragma unroll
      for (int oh=0;oh<2;++oh)
        ka[jm][oh] = *(const bf16x8*)(Kb + (size_t)(j0 + NJ + jm*16)*CQ + oh*32);

    // ---- exp2, l partial, pack -> wave-private LDS ----
#pragma unroll
    for (int s=0;s<2;++s)
#pragma unroll
      for (int jm=0;jm<4;++jm){
        const float p0 = __builtin_amdgcn_exp2f(sf[jm][s][0]);
        const float p1 = __builtin_amdgcn_exp2f(sf[jm][s][1]);
        const float p2 = __builtin_amdgcn_exp2f(sf[jm][s][2]);
        const float p3 = __builtin_amdgcn_exp2f(sf[jm][s][3]);
        lpart[s] += (p0+p1) + (p2+p3);
        pscr[wa + jm*288 + s*16]      = pack2bf(p0, p1);
        pscr[wa + jm*288 + s*16 + 36] = pack2bf(p2, p3);
      }

    // drain own DS writes (wave-local; NO barrier)
    __builtin_amdgcn_s_waitcnt(0xc07f);

    // ---- read P B-frags back (layout exchange along q) ----
    unsigned pd[2][2][4];
#pragma unroll
    for (int s=0;s<2;++s)
#pragma unroll
      for (int kh=0;kh<2;++kh)
#pragma unroll
        for (int d=0;d<4;++d)
          pd[s][kh][d] = pscr[ra + kh*576 + s*16 + d*36];

    // ---- V loads, second half (cs 4..7) ----
#pragma unroll
    for (int cs=4;cs<8;++cs)
#pragma unroll
      for (int kh=0;kh<2;++kh)
        va[cs][kh] = *(const bf16x8*)(Vb + (size_t)cs*16*NN + j0 + kh*32);

    bf16x8 pb[2][2];
#pragma unroll
    for (int s=0;s<2;++s)
#pragma unroll
      for (int kh=0;kh<2;++kh){
        union { unsigned u[4]; bf16x8 v; } uu;
        uu.u[0] = pd[s][kh][0];
        uu.u[1] = pd[s][kh][1];
        uu.u[2] = pd[s][kh][2];
        uu.u[3] = pd[s][kh][3];
        pb[s][kh] = uu.v;
      }

    // ---- PV: 32 MFMA (8 c-tiles x 2 i-groups x K=64) ----
#pragma unroll
    for (int cs=0;cs<8;++cs)
#pragma unroll
      for (int s=0;s<2;++s){
        acc[cs][s] = __builtin_amdgcn_mfma_f32_16x16x32_bf16(va[cs][0], pb[s][0], acc[cs][s], 0,0,0);
        acc[cs][s] = __builtin_amdgcn_mfma_f32_16x16x32_bf16(va[cs][1], pb[s][1], acc[cs][s], 0,0,0);
      }
  }

  // ---- l reduction: only across q-groups (wave-local, complete) ----
  float linv[2];
#pragma unroll
  for (int s=0;s<2;++s){
    lpart[s] += __shfl_xor(lpart[s], 16, 64);
    lpart[s] += __shfl_xor(lpart[s], 32, 64);
    linv[s] = 1.0f / lpart[s];
  }

  const float gam = gamma[0];
#pragma unroll
  for (int cs=0;cs<8;++cs){
#pragma unroll
    for (int s=0;s<2;++s){
      const int cb = c0w + cs*16 + q*4;
      const int i  = i0w + s*16 + iq;
#pragma unroll
      for (int r=0;r<4;++r){
        const size_t idx = ((size_t)b*CC + cb + r)*NN + i;
        out[idx] = fmaf(gam, acc[cs][s][r]*linv[s], x[idx]);
      }
    }
  }
}

extern "C" void kernel_launch(void* const* d_in, const int* in_sizes, int n_in,
                              void* d_out, int out_size, void* d_ws, size_t ws_size,
                              hipStream_t stream){
  const float* x     = (const float*)d_in[0];
  const float* Wq    = (const float*)d_in[1];
  const float* bq    = (const float*)d_in[2];
  const float* Wk    = (const float*)d_in[3];
  const float* bk    = (const float*)d_in[4];
  const float* Wv    = (const float*)d_in[5];
  const float* bv    = (const float*)d_in[6];
  const float* gamma = (const float*)d_in[7];
  float* out = (float*)d_out;

  // workspace: xT bf16 [8][4096][512] 33.6MB; Qbf/Kbf bf16 [8][4096][64] 4.2MB each;
  // Vbf bf16 [8][512][4096] 33.6MB; Wqkbf [128][512] 128KB; Wvbf [512][512] 512KB. ~76 MB
  short* xTbf = (short*)d_ws;
  short* Qbf  = xTbf + (size_t)BB*NN*CC;
  short* Kbf  = Qbf  + (size_t)BB*NN*CQ;
  short* Vbf  = Kbf  + (size_t)BB*NN*CQ;
  short* Wqkbf= Vbf  + (size_t)BB*CC*NN;
  short* Wvbf = Wqkbf + (size_t)2*CQ*CC;

  cvt_w_kernel<<<dim3(CC*CC/256), 256, 0, stream>>>(Wq, Wk, Wv, Wqkbf, Wvbf);
  cvt_x_kernel<<<dim3(NN/64, CC/64, BB), 256, 0, stream>>>(x, xTbf);
  proj_qk_mfma<<<dim3(NN/128, 1, BB), 256, 0, stream>>>(xTbf, Wqkbf, bq, bk, Qbf, Kbf);
  proj_v_mfma<<<dim3(NN/64, CC/128, BB), 256, 0, stream>>>(xTbf, Wvbf, bv, Vbf);
  attn_mfma_kernel<<<dim3(BB*NN*2/MQ), 256, 0, stream>>>(Qbf, Kbf, Vbf, x, gamma, out);
}

// Round 6
// 508.299 us; speedup vs baseline: 1.8069x; 1.8069x over previous
//
#include <hip/hip_runtime.h>
#include <hip/hip_bf16.h>
#include <cstddef>

#define BB 8
#define CC 512
#define NN 4096
#define CQ 64
#define MQ 64   // Q-rows per attn block
#define NJ 64   // j-tile

typedef short bf16x8 __attribute__((ext_vector_type(8)));
typedef float f32x4  __attribute__((ext_vector_type(4)));

// fp32 -> bf16 bits, round-to-nearest-even
static __device__ __forceinline__ unsigned bf16_bits(float f){
  unsigned u = __float_as_uint(f);
  u += 0x7fffu + ((u >> 16) & 1u);
  return u >> 16;
}
static __device__ __forceinline__ unsigned pack2bf(float lo, float hi){
  return bf16_bits(lo) | (bf16_bits(hi) << 16);
}

// ---- weights fp32 -> bf16 (Wqk packed: rows 0..63 = Wq, 64..127 = Wk) ----
__global__ __launch_bounds__(256) void cvt_w_kernel(
    const float* __restrict__ Wq, const float* __restrict__ Wk,
    const float* __restrict__ Wv,
    short* __restrict__ Wqkbf, short* __restrict__ Wvbf){
  const int i = blockIdx.x*256 + threadIdx.x;
  if (i < CQ*CC){
    Wqkbf[i]         = (short)bf16_bits(Wq[i]);
    Wqkbf[CQ*CC + i] = (short)bf16_bits(Wk[i]);
  }
  Wvbf[i] = (short)bf16_bits(Wv[i]);
}

// ---- x fp32 [b][c][n] -> xT bf16 [b][n][c] via LDS 64x64 tile ----
// Reads vectorized: float4 per lane (4x fewer global load instructions).
__global__ __launch_bounds__(256) void cvt_x_kernel(
    const float* __restrict__ x, short* __restrict__ xT){
  __shared__ float lds[64*67];
  const int tid = threadIdx.x;
  const int n0 = blockIdx.x*64, c0 = blockIdx.y*64, b = blockIdx.z;
  const float* xp = x + ((size_t)b*CC + c0)*NN + n0;
  const int n4  = (tid & 15)*4;
  const int cl0 = tid >> 4;        // 0..15
#pragma unroll
  for (int i=0;i<4;++i){
    const int cl = cl0 + i*16;
    const float4 v = *(const float4*)(xp + (size_t)cl*NN + n4);
    lds[(n4+0)*67 + cl] = v.x;
    lds[(n4+1)*67 + cl] = v.y;
    lds[(n4+2)*67 + cl] = v.z;
    lds[(n4+3)*67 + cl] = v.w;
  }
  __syncthreads();
  short* xTp = xT + ((size_t)b*NN + n0)*CC + c0;
#pragma unroll
  for (int p=0;p<2;++p){
    const int nl2 = (tid>>3) + p*32;
    const int c8 = (tid&7)*8;
    const float* r = &lds[nl2*67 + c8];
    uint4 v;
    v.x = pack2bf(r[0], r[1]);
    v.y = pack2bf(r[2], r[3]);
    v.z = pack2bf(r[4], r[5]);
    v.w = pack2bf(r[6], r[7]);
    *(uint4*)&xTp[(size_t)nl2*CC + c8] = v;
  }
}

// ---- Q,K projection via MFMA: D[n][o] = xT . Wqk^T;  Qbf/Kbf layout [b][n][64] ----
// Q is pre-scaled by log2(e) so attn can use raw v_exp_f32 (2^x).
__global__ __launch_bounds__(256) void proj_qk_mfma(
    const short* __restrict__ xT, const short* __restrict__ Wqkbf,
    const float* __restrict__ bq, const float* __restrict__ bk,
    short* __restrict__ Qbf, short* __restrict__ Kbf){
  const int tid  = threadIdx.x;
  const int lane = tid & 63;
  const int w    = tid >> 6;
  const int iq   = lane & 15;
  const int q    = lane >> 4;
  const int b    = blockIdx.z;
  const int n0w  = blockIdx.x*128 + w*32;

  f32x4 acc[2][8];
#pragma unroll
  for (int ns=0;ns<2;++ns)
#pragma unroll
    for (int os=0;os<8;++os) acc[ns][os] = (f32x4){0.f,0.f,0.f,0.f};

  const short* Abase = xT + ((size_t)b*NN + n0w + iq)*CC + q*8;
  const short* Bbase = Wqkbf + (size_t)iq*CC + q*8;

  for (int ks=0; ks<16; ++ks){
    const int k = ks*32;
    bf16x8 af[2], bf[8];
#pragma unroll
    for (int ns=0;ns<2;++ns) af[ns] = *(const bf16x8*)(Abase + (size_t)ns*16*CC + k);
#pragma unroll
    for (int os=0;os<8;++os) bf[os] = *(const bf16x8*)(Bbase + (size_t)os*16*CC + k);
#pragma unroll
    for (int ns=0;ns<2;++ns)
#pragma unroll
      for (int os=0;os<8;++os)
        acc[ns][os] = __builtin_amdgcn_mfma_f32_16x16x32_bf16(af[ns], bf[os], acc[ns][os], 0,0,0);
  }
#pragma unroll
  for (int ns=0;ns<2;++ns){
#pragma unroll
    for (int os=0;os<8;++os){
      const int o = (os&4) ? ((os-4)*16 + iq) : (os*16 + iq);
      const float bias = (os<4) ? bq[o] : bk[o];
      short* dst = (os<4) ? Qbf : Kbf;
#pragma unroll
      for (int r=0;r<4;++r){
        const int n = n0w + ns*16 + q*4 + r;
        float v = acc[ns][os][r] + bias;
        if (os < 4) v *= 1.44269504088896f;  // fold log2(e) into Q
        dst[((size_t)b*NN + n)*CQ + o] = (short)bf16_bits(v);
      }
    }
  }
}

// ---- V projection via MFMA: D[c][n] = Wv . x;  Vbf layout [b][c][n] ----
// 64c x 64n per wave (acc[4][4]): 16 MFMA per 8 loads per ks (2x density of old 8/6).
__global__ __launch_bounds__(256) void proj_v_mfma(
    const short* __restrict__ xT, const short* __restrict__ Wvbf,
    const float* __restrict__ bv, short* __restrict__ Vbf){
  const int tid  = threadIdx.x;
  const int lane = tid & 63;
  const int w    = tid >> 6;
  const int iq   = lane & 15;
  const int q    = lane >> 4;
  const int b    = blockIdx.z;
  const int c0w  = blockIdx.y*128 + (w&1)*64;
  const int n0w  = blockIdx.x*128 + (w>>1)*64;

  f32x4 acc[4][4];   // [cs][ns]
#pragma unroll
  for (int cs=0;cs<4;++cs)
#pragma unroll
    for (int ns=0;ns<4;++ns) acc[cs][ns] = (f32x4){0.f,0.f,0.f,0.f};

  const short* Abase = Wvbf + (size_t)(c0w + iq)*CC + q*8;
  const short* Bbase = xT + ((size_t)b*NN + n0w + iq)*CC + q*8;

  for (int ks=0; ks<16; ++ks){
    const int k = ks*32;
    bf16x8 af[4], bf[4];
#pragma unroll
    for (int cs=0;cs<4;++cs) af[cs] = *(const bf16x8*)(Abase + (size_t)cs*16*CC + k);
#pragma unroll
    for (int ns=0;ns<4;++ns) bf[ns] = *(const bf16x8*)(Bbase + (size_t)ns*16*CC + k);
#pragma unroll
    for (int cs=0;cs<4;++cs)
#pragma unroll
      for (int ns=0;ns<4;++ns)
        acc[cs][ns] = __builtin_amdgcn_mfma_f32_16x16x32_bf16(af[cs], bf[ns], acc[cs][ns], 0,0,0);
  }
#pragma unroll
  for (int cs=0;cs<4;++cs){
#pragma unroll
    for (int r=0;r<4;++r){
      const int c = c0w + cs*16 + q*4 + r;
      const float bias = bv[c];
#pragma unroll
      for (int ns=0;ns<4;++ns){
        const int n = n0w + ns*16 + iq;
        Vbf[((size_t)b*CC + c)*NN + n] = (short)bf16_bits(acc[cs][ns][r] + bias);
      }
    }
  }
}

// ---- MFMA flash attention (r0 structure, register-lean) ----
// Grid 1024: bid&7 = batch (XCD swizzle), (bid>>3)&1 = c-half (256 ch), bid>>4 = i-tile.
// P tile LDS: 16-B chunk per (j-octet jo 0..7, i 0..63); double-buffered.
// One lgkm-only barrier per jt (global loads stay in flight).
// Register diet (target: total arch+acc <= 170 -> 3 waves/SIMD granted by HW):
//   - K single-buffered, reloaded for jt+1 after QK consumes it (saves 16 vs r0)
//   - exp applied per-s immediately after its 2 QK MFMAs (sf live = 4 regs, not 16)
// No forced occupancy bound: if allocation lands high we stay at 2 waves (neutral).
__global__ __launch_bounds__(256, 2) void attn_mfma_kernel(
    const short* __restrict__ Qbf, const short* __restrict__ Kbf,
    const short* __restrict__ Vbf, const float* __restrict__ x,
    const float* __restrict__ gamma, float* __restrict__ out){
  __shared__ unsigned plds[2][2048];
  __shared__ float lsum[4][MQ];

  const int tid  = threadIdx.x;
  const int lane = tid & 63;
  const int w    = tid >> 6;
  const int iq   = lane & 15;
  const int q    = lane >> 4;
  const int bid  = blockIdx.x;
  const int b    = bid & 7;
  const int ch   = ((bid >> 3) & 1) * 256;
  const int i0   = (bid >> 4) * MQ;

  // Q B-frags (persistent), pre-scaled by log2(e) in proj
  bf16x8 qb[4][2];
#pragma unroll
  for (int s=0;s<4;++s){
    const short* qp = Qbf + ((size_t)b*NN + i0 + s*16 + iq)*CQ + q*8;
    qb[s][0] = *(const bf16x8*)qp;
    qb[s][1] = *(const bf16x8*)(qp + 32);
  }

  f32x4 acc[4][4];
#pragma unroll
  for (int cs=0;cs<4;++cs)
#pragma unroll
    for (int s=0;s<4;++s) acc[cs][s] = (f32x4){0.f,0.f,0.f,0.f};
  float lpart[4] = {0.f,0.f,0.f,0.f};

  const short* Kbase = Kbf + ((size_t)b*NN + w*16 + iq)*CQ + q*8;        // A[m=j][k=o]
  const short* Vbase = Vbf + ((size_t)b*CC + ch + w*64 + iq)*NN + q*8;   // A[m=c][k=j]

  // LDS dword offsets: producer writes chunk jo=w*2+(q>>1), consumer reads jo=q+4*ks
  const int woff  = (w*2 + (q>>1))*256 + iq*4 + (q&1)*2;   // + s*64
  const int roff0 = q*256 + iq*4;                          // + s*64 (+1024 for ks=1)

  // K frags for jt=0 (single buffer; reloaded each jt after QK consumes them)
  bf16x8 ka0 = *(const bf16x8*)Kbase;
  bf16x8 ka1 = *(const bf16x8*)(Kbase + 32);

#pragma unroll 2
  for (int jt=0; jt<NN/NJ; ++jt){
    const int buf = jt & 1;
    const int j0 = jt*NJ;

    // ---- issue V loads for THIS jt (consumed after barrier; distance proven OK in r2) ----
    bf16x8 va[4][2];
    const short* vp = Vbase + j0;
#pragma unroll
    for (int cs=0;cs<4;++cs){
      const short* vrow = vp + (size_t)cs*16*NN;
      va[cs][0] = *(const bf16x8*)vrow;
      va[cs][1] = *(const bf16x8*)(vrow + 32);
    }

    // ---- S^T = K . Q^T, exp per-s immediately (sf live = 1x f32x4) ----
#pragma unroll
    for (int s=0;s<4;++s){
      f32x4 sfs;
      sfs = __builtin_amdgcn_mfma_f32_16x16x32_bf16(ka0, qb[s][0], (f32x4){0.f,0.f,0.f,0.f}, 0,0,0);
      sfs = __builtin_amdgcn_mfma_f32_16x16x32_bf16(ka1, qb[s][1], sfs, 0,0,0);
      const float p0 = __builtin_amdgcn_exp2f(sfs[0]);
      const float p1 = __builtin_amdgcn_exp2f(sfs[1]);
      const float p2 = __builtin_amdgcn_exp2f(sfs[2]);
      const float p3 = __builtin_amdgcn_exp2f(sfs[3]);
      lpart[s] += (p0+p1) + (p2+p3);
      uint2 pw;
      pw.x = pack2bf(p0, p1);
      pw.y = pack2bf(p2, p3);
      *(uint2*)&plds[buf][woff + s*64] = pw;   // ds_write_b64
    }

    // ---- reload K for jt+1 (use is after barrier+PV: ~600+ cyc of slack;
    //      overread past Kbf end stays inside workspace, unused) ----
    {
      const short* kp = Kbase + (size_t)(j0 + NJ)*CQ;
      ka0 = *(const bf16x8*)kp;
      ka1 = *(const bf16x8*)(kp + 32);
    }

    // ---- LDS-only barrier: wait lgkmcnt(0), leave vmcnt in flight ----
    __builtin_amdgcn_s_waitcnt(0xc07f);
    __builtin_amdgcn_s_barrier();

    // ---- PV: B-frags from LDS, A = V fragments issued this jt ----
#pragma unroll
    for (int s=0;s<4;++s){
      const bf16x8 pb0 = *(const bf16x8*)&plds[buf][roff0 + s*64];
      const bf16x8 pb1 = *(const bf16x8*)&plds[buf][roff0 + s*64 + 1024];
#pragma unroll
      for (int cs=0;cs<4;++cs){
        acc[cs][s] = __builtin_amdgcn_mfma_f32_16x16x32_bf16(va[cs][0], pb0, acc[cs][s], 0,0,0);
        acc[cs][s] = __builtin_amdgcn_mfma_f32_16x16x32_bf16(va[cs][1], pb1, acc[cs][s], 0,0,0);
      }
    }
  }

  // ---- l reduction ----
#pragma unroll
  for (int s=0;s<4;++s){
    lpart[s] += __shfl_xor(lpart[s], 16, 64);
    lpart[s] += __shfl_xor(lpart[s], 32, 64);
  }
  __syncthreads();
  if (q == 0){
#pragma unroll
    for (int s=0;s<4;++s) lsum[w][s*16 + iq] = lpart[s];
  }
  __syncthreads();
  float linv[4];
#pragma unroll
  for (int s=0;s<4;++s){
    const int i = s*16 + iq;
    linv[s] = 1.0f / (lsum[0][i] + lsum[1][i] + lsum[2][i] + lsum[3][i]);
  }

  const float gam = gamma[0];
#pragma unroll
  for (int cs=0;cs<4;++cs){
#pragma unroll
    for (int s=0;s<4;++s){
      const int cb = ch + w*64 + cs*16 + q*4;
      const int i  = i0 + s*16 + iq;
#pragma unroll
      for (int r=0;r<4;++r){
        const size_t idx = ((size_t)b*CC + cb + r)*NN + i;
        out[idx] = fmaf(gam, acc[cs][s][r]*linv[s], x[idx]);
      }
    }
  }
}

extern "C" void kernel_launch(void* const* d_in, const int* in_sizes, int n_in,
                              void* d_out, int out_size, void* d_ws, size_t ws_size,
                              hipStream_t stream){
  const float* x     = (const float*)d_in[0];
  const float* Wq    = (const float*)d_in[1];
  const float* bq    = (const float*)d_in[2];
  const float* Wk    = (const float*)d_in[3];
  const float* bk    = (const float*)d_in[4];
  const float* Wv    = (const float*)d_in[5];
  const float* bv    = (const float*)d_in[6];
  const float* gamma = (const float*)d_in[7];
  float* out = (float*)d_out;

  // workspace: xT bf16 [8][4096][512] 33.6MB; Qbf/Kbf bf16 [8][4096][64] 4.2MB each;
  // Vbf bf16 [8][512][4096] 33.6MB; Wqkbf [128][512] 128KB; Wvbf [512][512] 512KB. ~76 MB
  short* xTbf = (short*)d_ws;
  short* Qbf  = xTbf + (size_t)BB*NN*CC;
  short* Kbf  = Qbf  + (size_t)BB*NN*CQ;
  short* Vbf  = Kbf  + (size_t)BB*NN*CQ;
  short* Wqkbf= Vbf  + (size_t)BB*CC*NN;
  short* Wvbf = Wqkbf + (size_t)2*CQ*CC;

  cvt_w_kernel<<<dim3(CC*CC/256), 256, 0, stream>>>(Wq, Wk, Wv, Wqkbf, Wvbf);
  cvt_x_kernel<<<dim3(NN/64, CC/64, BB), 256, 0, stream>>>(x, xTbf);
  proj_qk_mfma<<<dim3(NN/128, 1, BB), 256, 0, stream>>>(xTbf, Wqkbf, bq, bk, Qbf, Kbf);
  proj_v_mfma<<<dim3(NN/128, CC/128, BB), 256, 0, stream>>>(xTbf, Wvbf, bv, Vbf);
  attn_mfma_kernel<<<dim3(BB*NN*2/MQ), 256, 0, stream>>>(Qbf, Kbf, Vbf, x, gamma, out);
}